// Round 4
// baseline (254.456 us; speedup 1.0000x reference)
//
#include <hip/hip_runtime.h>

#define B_SZ 4096
#define S_SZ 128
#define XD 5
#define EH 128
#define DH 256
#define DSTEPS 10

typedef short v8s __attribute__((ext_vector_type(8)));
typedef float v4f __attribute__((ext_vector_type(4)));

__device__ __forceinline__ float bf2f(unsigned short u) {
    union { unsigned int i; float f; } v; v.i = ((unsigned int)u) << 16; return v.f;
}
__device__ __forceinline__ unsigned short f2bf(float f) {
    union { float f; unsigned int i; } v; v.f = f;
    unsigned int x = v.i;
    return (unsigned short)((x + 0x7FFFu + ((x >> 16) & 1u)) >> 16);
}
__device__ __forceinline__ float fexp2(float x) { return __builtin_amdgcn_exp2f(x); }
__device__ __forceinline__ float frcp(float x) { return __builtin_amdgcn_rcpf(x); }
__device__ __forceinline__ float sigmoidf_(float x) {
    return frcp(1.f + fexp2(-1.44269504088896f * x));
}
__device__ __forceinline__ float tanhf_(float x) {
    float e = fexp2(2.88539008177793f * x);   // e^(2x)
    return 1.f - 2.f * frcp(e + 1.f);
}
// cross-half pull with unambiguous semantics (ISA: ds_bpermute = "pull",
// v0 <- lane[addr>>2].src). Lane l receives src's value from lane l^32.
__device__ __forceinline__ float pull_x32(float v, int bpaddr) {
    union { float f; int i; } u; u.f = v;
    u.i = __builtin_amdgcn_ds_bpermute(bpaddr, u.i);
    return u.f;
}

// ---------------------------------------------------------------- encoder v3c
// 512 blocks x 256 thr (4 waves). Block = 8 batch rows x all 128 h-cols ->
// TWO independent barrier-groups per CU so the MFMA / VALU(trans) / LDS
// phases of out-of-phase blocks overlap (measured fully serialized in r0:
// 48% VALU + 22% MFMA + ~35% LDS ~= 100% of step time).
// Wave w owns cols [32w,32w+32) as 2 x 16-col groups; M=8 rides in a 16x16
// MFMA tile (rows 8-15 zero -> valid C lives in lanes 0-31 of each cg).
// Combine via ds_bpermute(lane^32) + select: lanes 0-31 keep acc[0], lanes
// 32-63 pull acc[1] from lane-32. Every lane finalizes exactly 4 elements.
// (v_permlane32_swap asm failed twice -> replaced with verified primitive.)
// Activation scale constants are folded into the bf16 weights/biases.
__global__ __launch_bounds__(256, 2) void enc_kernel(
    const float* __restrict__ x,       // [B][S][5] fp32
    const float* __restrict__ Wih32,   // [384][5] fp32
    const float* __restrict__ Whh32,   // [384][128] fp32
    const float* __restrict__ bih,     // [384] fp32
    const float* __restrict__ bhh,     // [384] fp32
    const float* __restrict__ dWih,    // [768][129] fp32
    const float* __restrict__ dWhh,    // [768][256] fp32
    unsigned short* __restrict__ wihp,     // out: [768][136] bf16 (col128=y wt)
    unsigned short* __restrict__ dWhh_bf,  // out: [768][256] bf16
    unsigned short* __restrict__ ctex)     // out: [B][128] bf16
{
    __shared__ unsigned short xs[S_SZ][8][8];      // 16 KB
    __shared__ unsigned short hb[2][16][136];      // 8.5 KB (rows 8-15 stay 0)
    __shared__ __align__(16) unsigned short zpad[8];

    const int tid = threadIdx.x;
    const int bid = blockIdx.x;
    const int wv = tid >> 6;
    const int lane = tid & 63;
    const int n = lane & 15;
    const int kg = lane >> 4;
    const int r0 = bid * 8;
    const int cbase = wv * 32;
    const int bpaddr = (lane ^ 32) << 2;      // ds_bpermute byte addr

    // side-job: decoder weight conversion (grid-stride over 131072 threads)
    for (int i = bid * 256 + tid; i < 768 * 256; i += 131072)
        dWhh_bf[i] = f2bf(dWhh[i]);
    for (int i = bid * 256 + tid; i < 768 * 136; i += 131072) {
        int col = i / 136, k = i - col * 136;
        wihp[i] = (k < 129) ? f2bf(dWih[col * 129 + k]) : (unsigned short)0;
    }

    for (int i = tid; i < 2 * 16 * 136; i += 256) ((unsigned short*)hb)[i] = 0;
    if (tid < 8) zpad[tid] = 0;
    for (int i = tid; i < 8 * S_SZ * 8; i += 256) {
        int m = i >> 10;
        int rem = i & 1023;
        int t = rem >> 3;
        int j = rem & 7;
        unsigned short v = 0;
        if (j < XD) v = f2bf(x[(size_t)(r0 + m) * (S_SZ * XD) + t * XD + j]);
        xs[t][m][j] = v;
    }

    // per-wave weights, 2 col-groups, scale constants folded in
    v8s fw[3][2][4];
    v8s fx[3][2];
    #pragma unroll
    for (int g = 0; g < 3; ++g) {
        const float sc = (g < 2) ? -1.44269504088896f : 2.88539008177793f;
        #pragma unroll
        for (int cg = 0; cg < 2; ++cg) {
            const int gcol = g * EH + cbase + cg * 16 + n;
            #pragma unroll
            for (int kt = 0; kt < 4; ++kt) {
                const float* p = &Whh32[(size_t)gcol * EH + kt * 32 + kg * 8];
                float4 lo = *(const float4*)p;
                float4 hi = *(const float4*)(p + 4);
                v8s f;
                f[0] = (short)f2bf(sc * lo.x); f[1] = (short)f2bf(sc * lo.y);
                f[2] = (short)f2bf(sc * lo.z); f[3] = (short)f2bf(sc * lo.w);
                f[4] = (short)f2bf(sc * hi.x); f[5] = (short)f2bf(sc * hi.y);
                f[6] = (short)f2bf(sc * hi.z); f[7] = (short)f2bf(sc * hi.w);
                fw[g][cg][kt] = f;
            }
            v8s tv = {0, 0, 0, 0, 0, 0, 0, 0};
            if (kg == 0) {
                const float* p = &Wih32[gcol * XD];
                #pragma unroll
                for (int j = 0; j < XD; ++j) tv[j] = (short)f2bf(sc * p[j]);
            }
            fx[g][cg] = tv;
        }
    }
    float br[2], bz[2], bin_[2], bhn[2];
    #pragma unroll
    for (int cg = 0; cg < 2; ++cg) {
        const int c0 = cbase + cg * 16 + n;
        br[cg]   = -1.44269504088896f * (bih[c0] + bhh[c0]);
        bz[cg]   = -1.44269504088896f * (bih[EH + c0] + bhh[EH + c0]);
        bin_[cg] =  2.88539008177793f * bih[2 * EH + c0];
        bhn[cg]  =  2.88539008177793f * bhh[2 * EH + c0];
    }

    const int hi_half = kg >> 1;              // which cg this lane finalizes
    const int colw = cbase + hi_half * 16 + n;
    const int rquad = (kg & 1) * 4;           // row quad within the 8 rows

    float hst[4] = {0.f, 0.f, 0.f, 0.f};
    __syncthreads();

    #pragma unroll 2
    for (int t = 0; t < S_SZ; ++t) {
        const int p = t & 1;
        v8s a[4];
        #pragma unroll
        for (int kt = 0; kt < 4; ++kt)
            a[kt] = *(const v8s*)&hb[p][n][kt * 32 + kg * 8];
        const unsigned short* xsrc = (kg == 0 && n < 8) ? &xs[t][n][0] : &zpad[0];
        v8s ax = *(const v8s*)xsrc;

        v4f accr[2], accz[2], acchn[2], accin[2];
        #pragma unroll
        for (int cg = 0; cg < 2; ++cg) {
            accr[cg]  = (v4f){br[cg], br[cg], br[cg], br[cg]};
            accz[cg]  = (v4f){bz[cg], bz[cg], bz[cg], bz[cg]};
            acchn[cg] = (v4f){bhn[cg], bhn[cg], bhn[cg], bhn[cg]};
            accin[cg] = (v4f){bin_[cg], bin_[cg], bin_[cg], bin_[cg]};
        }
        #pragma unroll
        for (int kt = 0; kt < 4; ++kt) {
            #pragma unroll
            for (int cg = 0; cg < 2; ++cg) {
                accr[cg]  = __builtin_amdgcn_mfma_f32_16x16x32_bf16(a[kt], fw[0][cg][kt], accr[cg], 0, 0, 0);
                accz[cg]  = __builtin_amdgcn_mfma_f32_16x16x32_bf16(a[kt], fw[1][cg][kt], accz[cg], 0, 0, 0);
                acchn[cg] = __builtin_amdgcn_mfma_f32_16x16x32_bf16(a[kt], fw[2][cg][kt], acchn[cg], 0, 0, 0);
            }
        }
        #pragma unroll
        for (int cg = 0; cg < 2; ++cg) {
            accr[cg]  = __builtin_amdgcn_mfma_f32_16x16x32_bf16(ax, fx[0][cg], accr[cg], 0, 0, 0);
            accz[cg]  = __builtin_amdgcn_mfma_f32_16x16x32_bf16(ax, fx[1][cg], accz[cg], 0, 0, 0);
            accin[cg] = __builtin_amdgcn_mfma_f32_16x16x32_bf16(ax, fx[2][cg], accin[cg], 0, 0, 0);
        }

        // combine: lanes 0-31 keep acc[0] (valid rows 0-7 of cg0);
        // lanes 32-63 pull acc[1] from lane-32 (valid rows 0-7 of cg1).
        #pragma unroll
        for (int e = 0; e < 4; ++e) {
            float tr  = pull_x32(accr[1][e],  bpaddr);
            float tz  = pull_x32(accz[1][e],  bpaddr);
            float thn = pull_x32(acchn[1][e], bpaddr);
            float tin = pull_x32(accin[1][e], bpaddr);
            float vr  = hi_half ? tr  : accr[0][e];
            float vz  = hi_half ? tz  : accz[0][e];
            float vhn = hi_half ? thn : acchn[0][e];
            float vin = hi_half ? tin : accin[0][e];
            float r  = frcp(1.f + fexp2(vr));                     // scales folded
            float z  = frcp(1.f + fexp2(vz));
            float nn = 1.f - 2.f * frcp(fexp2(vin + r * vhn) + 1.f);
            float h  = nn + z * (hst[e] - nn);
            hst[e] = h;
            hb[1 - p][rquad + e][colw] = f2bf(h);
        }
        __syncthreads();
    }
    #pragma unroll
    for (int e = 0; e < 4; ++e)
        ctex[(size_t)(r0 + rquad + e) * EH + colw] = f2bf(hst[e]);
}

// ---------------------------------------------------------------- fused decoder v2
// (unchanged this round — will be profiled next round when it becomes the
// top dispatch)
__global__ __launch_bounds__(512)
__attribute__((amdgpu_waves_per_eu(2, 2)))
void dec_all_kernel(
    const unsigned short* __restrict__ dWhh_bf, // [768][256] bf16
    const unsigned short* __restrict__ wihp,    // [768][136] bf16
    const float* __restrict__ dbih,   // [768]
    const float* __restrict__ dbhh,   // [768]
    const float* __restrict__ y,      // [B][128] fp32
    const unsigned short* __restrict__ ctex,  // [B][128] bf16
    const float* __restrict__ linW,   // [4][256] fp32
    const float* __restrict__ linb,   // [4] fp32
    float* __restrict__ out)          // [B][S][4] fp32
{
    __shared__ unsigned short wshn[32 * 264 * 8];  // 132 KB n-gate Whh (frag, pad 264)
    __shared__ unsigned short hshf[32 * 16 * 8];   // 8 KB   h state (frag)
    __shared__ unsigned short lwf[32 * 16 * 8];    // 8 KB   linW (frag, 4->16 pad)

    const int tid  = threadIdx.x;
    const int w    = tid >> 6;
    const int lane = tid & 63;
    const int n    = lane & 15;
    const int kg   = lane >> 4;
    const int rb   = blockIdx.x * 16;
    const int cbase = w * 32;

    // stage n-gate Whh (once; coalesced global reads)
    for (int i = tid; i < 256 * 32; i += 512) {
        int col = i >> 5, kgrp = i & 31;
        uint4 v = *(const uint4*)&dWhh_bf[(size_t)(512 + col) * 256 + kgrp * 8];
        *(uint4*)&wshn[(kgrp * 264 + col) * 8] = v;
    }
    // stage linW into frag layout
    {
        int col = tid >> 5, kgrp = tid & 31;
        unsigned short v8[8];
        #pragma unroll
        for (int j = 0; j < 8; ++j)
            v8[j] = (col < 4) ? f2bf(linW[col * 256 + kgrp * 8 + j]) : (unsigned short)0;
        *(uint4*)&lwf[(kgrp * 16 + col) * 8] = *(uint4*)v8;
    }
    // h0 = 1
    for (int i = tid; i < 32 * 16 * 8; i += 512) hshf[i] = 0x3F80;

    // resident r/z B-frags: 2 gates x 2 colgroups x 8 K-tiles = 128 VGPRs
    v8s fB[2][2][8];
    #pragma unroll
    for (int g = 0; g < 2; ++g)
        #pragma unroll
        for (int cg = 0; cg < 2; ++cg)
            #pragma unroll
            for (int kt = 0; kt < 8; ++kt)
                fB[g][cg][kt] = *(const v8s*)
                    &dWhh_bf[(size_t)(g * DH + cbase + cg * 16 + n) * DH + kt * 32 + kg * 8];

    // gi = ctex @ dWih[:, :128]^T + dbih (+dbhh for r,z); y weight per col
    v4f gi[3][2];
    float wy[3][2], bNh[2];
    #pragma unroll
    for (int g = 0; g < 3; ++g)
        #pragma unroll
        for (int cg = 0; cg < 2; ++cg) {
            int gcol = g * DH + cbase + cg * 16 + n;
            float bb = dbih[gcol] + ((g < 2) ? dbhh[gcol] : 0.f);
            gi[g][cg] = (v4f){bb, bb, bb, bb};
            wy[g][cg] = bf2f(wihp[(size_t)gcol * 136 + 128]);
        }
    #pragma unroll
    for (int cg = 0; cg < 2; ++cg)
        bNh[cg] = dbhh[2 * DH + cbase + cg * 16 + n];

    #pragma unroll
    for (int kt = 0; kt < 4; ++kt) {
        v8s a = *(const v8s*)&ctex[(size_t)(rb + n) * EH + kt * 32 + kg * 8];
        #pragma unroll
        for (int g = 0; g < 3; ++g)
            #pragma unroll
            for (int cg = 0; cg < 2; ++cg) {
                v8s b = *(const v8s*)
                    &wihp[(size_t)(g * DH + cbase + cg * 16 + n) * 136 + kt * 32 + kg * 8];
                gi[g][cg] = __builtin_amdgcn_mfma_f32_16x16x32_bf16(a, b, gi[g][cg], 0, 0, 0);
            }
    }

    const float lb = (n < 4) ? linb[n] : 0.f;
    float hprev[2][4];
    #pragma unroll
    for (int cg = 0; cg < 2; ++cg)
        #pragma unroll
        for (int e = 0; e < 4; ++e) hprev[cg][e] = 1.0f;

    __syncthreads();

    for (int t = 0; t < DSTEPS; ++t) {
        float yv[4];
        #pragma unroll
        for (int e = 0; e < 4; ++e)
            yv[e] = y[(size_t)(rb + kg * 4 + e) * S_SZ + t];

        v4f ar[2], az[2], an[2];
        #pragma unroll
        for (int cg = 0; cg < 2; ++cg) {
            ar[cg] = (v4f){0.f, 0.f, 0.f, 0.f};
            az[cg] = (v4f){0.f, 0.f, 0.f, 0.f};
            an[cg] = (v4f){bNh[cg], bNh[cg], bNh[cg], bNh[cg]};
        }
        #pragma unroll
        for (int kt = 0; kt < 8; ++kt) {
            v8s a = *(const v8s*)&hshf[((kt * 4 + kg) * 16 + n) * 8];
            #pragma unroll
            for (int cg = 0; cg < 2; ++cg) {
                v8s bn_ = *(const v8s*)&wshn[((kt * 4 + kg) * 264 + cbase + cg * 16 + n) * 8];
                ar[cg] = __builtin_amdgcn_mfma_f32_16x16x32_bf16(a, fB[0][cg][kt], ar[cg], 0, 0, 0);
                az[cg] = __builtin_amdgcn_mfma_f32_16x16x32_bf16(a, fB[1][cg][kt], az[cg], 0, 0, 0);
                an[cg] = __builtin_amdgcn_mfma_f32_16x16x32_bf16(a, bn_,           an[cg], 0, 0, 0);
            }
        }
        __syncthreads();   // all reads of h_t complete

        #pragma unroll
        for (int cg = 0; cg < 2; ++cg) {
            const int chi = 4 * w + 2 * cg + (n >> 3);   // (col>>3)
            #pragma unroll
            for (int e = 0; e < 4; ++e) {
                float r  = sigmoidf_(gi[0][cg][e] + yv[e] * wy[0][cg] + ar[cg][e]);
                float z  = sigmoidf_(gi[1][cg][e] + yv[e] * wy[1][cg] + az[cg][e]);
                float nn = tanhf_(gi[2][cg][e] + yv[e] * wy[2][cg] + r * an[cg][e]);
                float h  = nn + z * (hprev[cg][e] - nn);
                hprev[cg][e] = h;
                hshf[(chi * 16 + kg * 4 + e) * 8 + (n & 7)] = f2bf(h);
            }
        }
        __syncthreads();   // h_{t+1} visible

        if (w == 0) {      // out-proj (overlaps other waves' next MFMA phase)
            v4f o4 = {0.f, 0.f, 0.f, 0.f};
            #pragma unroll
            for (int kt = 0; kt < 8; ++kt) {
                v8s a = *(const v8s*)&hshf[((kt * 4 + kg) * 16 + n) * 8];
                v8s b = *(const v8s*)&lwf[((kt * 4 + kg) * 16 + n) * 8];
                o4 = __builtin_amdgcn_mfma_f32_16x16x32_bf16(a, b, o4, 0, 0, 0);
            }
            if (n < 4) {
                #pragma unroll
                for (int e = 0; e < 4; ++e)
                    out[(size_t)(rb + kg * 4 + e) * (S_SZ * 4) + t * 4 + n] = o4[e] + lb;
            }
        }
    }

    // tail pad: out[:, 10:, :] = 1.0
    for (int j = tid; j < 16 * 512; j += 512) {
        int row = j >> 9, c = j & 511;
        if (c >= DSTEPS * 4) out[(size_t)(rb + row) * 512 + c] = 1.0f;
    }
}

// ---------------------------------------------------------------- launch
extern "C" void kernel_launch(void* const* d_in, const int* in_sizes, int n_in,
                              void* d_out, int out_size, void* d_ws, size_t ws_size,
                              hipStream_t stream)
{
    const float* x    = (const float*)d_in[0];
    const float* y    = (const float*)d_in[1];
    const float* eWih = (const float*)d_in[2];
    const float* eWhh = (const float*)d_in[3];
    const float* ebih = (const float*)d_in[4];
    const float* ebhh = (const float*)d_in[5];
    const float* dWih = (const float*)d_in[6];
    const float* dWhh = (const float*)d_in[7];
    const float* dbih = (const float*)d_in[8];
    const float* dbhh = (const float*)d_in[9];
    const float* linW = (const float*)d_in[10];
    const float* linb = (const float*)d_in[11];
    float* out = (float*)d_out;

    char* ws = (char*)d_ws;
    // ws layout (bytes):
    //   wihp     @ 0      : 768*136*2 = 208896
    //   dWhh_bf  @ 208896 : 768*256*2 = 393216  -> 602112
    //   ctex     @ 602112 : 4096*128*2 = 1048576 -> 1650688
    unsigned short* wihp    = (unsigned short*)(ws);
    unsigned short* dWhh_bf = (unsigned short*)(ws + 208896);
    unsigned short* ctex    = (unsigned short*)(ws + 602112);

    enc_kernel<<<512, 256, 0, stream>>>(x, eWih, eWhh, ebih, ebhh,
                                        dWih, dWhh, wihp, dWhh_bf, ctex);
    dec_all_kernel<<<256, 512, 0, stream>>>(dWhh_bf, wihp, dbih, dbhh, y,
                                            ctex, linW, linb, out);
}

// Round 6
// 203.203 us; speedup vs baseline: 1.2522x; 1.2522x over previous
//
#include <hip/hip_runtime.h>

#define B_SZ 4096
#define S_SZ 128
#define XD 5
#define EH 128
#define DH 256
#define DSTEPS 10

typedef short v8s __attribute__((ext_vector_type(8)));
typedef float v4f __attribute__((ext_vector_type(4)));

__device__ __forceinline__ float bf2f(unsigned short u) {
    union { unsigned int i; float f; } v; v.i = ((unsigned int)u) << 16; return v.f;
}
__device__ __forceinline__ unsigned short f2bf(float f) {
    union { float f; unsigned int i; } v; v.f = f;
    unsigned int x = v.i;
    return (unsigned short)((x + 0x7FFFu + ((x >> 16) & 1u)) >> 16);
}
__device__ __forceinline__ float fexp2(float x) { return __builtin_amdgcn_exp2f(x); }
__device__ __forceinline__ float frcp(float x) { return __builtin_amdgcn_rcpf(x); }
// pack 2 f32 -> 1 u32 of 2 bf16 (low word = first operand). HW-verified
// primitive (guide T12, m214v22 refcheck'd on gfx950).
__device__ __forceinline__ unsigned int cvt2bf(float lo, float hi) {
    unsigned int r;
    asm("v_cvt_pk_bf16_f32 %0, %1, %2" : "=v"(r) : "v"(lo), "v"(hi));
    return r;
}

#define SC_S (-1.44269504088896f)   // sigmoid: rcp(1+exp2(SC_S*x))
#define SC_T ( 2.88539008177793f)   // tanh:    1-2*rcp(exp2(SC_T*x)+1)

// ---------------------------------------------------------------- encoder v4
// r6 topology restored (256 blocks x 512 thr, 16 rows, wave owns 16 cols;
// the M=8 / 2-blocks-per-CU experiment measured SLOWER: lockstep blocks
// don't overlap, and half-empty MFMA tiles doubled the MFMA bill).
// VALU diet instead (VALU was the largest pipe at 1084 cyc/step):
//  - exp2 scale constants folded into bf16 weights/biases (-3 mul/elem)
//  - biases folded into x-MFMA slot 5 (x pad slot = 1.0, weight = scaled
//    bias) -> all accumulators init from one hoisted zero reg (-15 movs)
//  - h -> bf16 via v_cvt_pk_bf16_f32 pairs (12 f2bf ops -> 4)
__global__ __launch_bounds__(512) void enc_kernel(
    const float* __restrict__ x,       // [B][S][5] fp32
    const float* __restrict__ Wih32,   // [384][5] fp32
    const float* __restrict__ Whh32,   // [384][128] fp32
    const float* __restrict__ bih,     // [384] fp32
    const float* __restrict__ bhh,     // [384] fp32
    const float* __restrict__ dWih,    // [768][129] fp32
    const float* __restrict__ dWhh,    // [768][256] fp32
    unsigned short* __restrict__ wihp,     // out: [768][136] bf16 (col128=y wt), SCALED
    unsigned short* __restrict__ dWhh_bf,  // out: [768][256] bf16, SCALED
    unsigned short* __restrict__ ctex)     // out: [B][128] bf16
{
    __shared__ unsigned short xs[S_SZ][16][8];     // 32 KB (slot5 = 1.0)
    __shared__ unsigned short hb[2][16][136];      // 8.5 KB, +8 pad
    __shared__ __align__(16) unsigned short zpad[8];

    const int tid = threadIdx.x;
    const int bid = blockIdx.x;
    const int wv = tid >> 6;
    const int lane = tid & 63;
    const int n = lane & 15;
    const int kg = lane >> 4;       // K-group / C-row quad
    const int r0 = bid * 16;

    // side-job: decoder weight conversion WITH activation scales folded in.
    // dWhh rows 0..511 = r,z gates (SC_S); rows 512..767 = n gate (SC_T).
    for (int i = bid * 512 + tid; i < 768 * 256; i += 131072) {
        const float sc = ((i >> 8) < 512) ? SC_S : SC_T;
        dWhh_bf[i] = f2bf(sc * dWhh[i]);
    }
    for (int i = bid * 512 + tid; i < 768 * 136; i += 131072) {
        int col = i / 136, k = i - col * 136;
        const float sc = (col < 512) ? SC_S : SC_T;
        wihp[i] = (k < 129) ? f2bf(sc * dWih[col * 129 + k]) : (unsigned short)0;
    }

    for (int i = tid; i < 2 * 16 * 136; i += 512) ((unsigned short*)hb)[i] = 0;
    if (tid < 8) zpad[tid] = 0;
    for (int i = tid; i < 16 * S_SZ * 8; i += 512) {
        int m = i >> 10;
        int rem = i & 1023;
        int t = rem >> 3;
        int j = rem & 7;
        unsigned short v = 0;
        if (j < XD) v = f2bf(x[(size_t)(r0 + m) * (S_SZ * XD) + t * XD + j]);
        else if (j == XD) v = 0x3F80;          // constant-1 bias carrier
        xs[t][m][j] = v;
    }

    const int colw = wv * 16 + n;
    v8s fw[3][4];
    v8s fx[3];
    #pragma unroll
    for (int g = 0; g < 3; ++g) {
        const float sc = (g < 2) ? SC_S : SC_T;
        const int gcol = g * EH + colw;
        #pragma unroll
        for (int kt = 0; kt < 4; ++kt) {
            const float* p = &Whh32[(size_t)gcol * EH + kt * 32 + kg * 8];
            float4 lo = *(const float4*)p;
            float4 hi = *(const float4*)(p + 4);
            v8s f;
            f[0] = (short)f2bf(sc * lo.x); f[1] = (short)f2bf(sc * lo.y);
            f[2] = (short)f2bf(sc * lo.z); f[3] = (short)f2bf(sc * lo.w);
            f[4] = (short)f2bf(sc * hi.x); f[5] = (short)f2bf(sc * hi.y);
            f[6] = (short)f2bf(sc * hi.z); f[7] = (short)f2bf(sc * hi.w);
            fw[g][kt] = f;
        }
        v8s t = {0, 0, 0, 0, 0, 0, 0, 0};
        if (kg == 0) {
            const float* p = &Wih32[gcol * XD];
            #pragma unroll
            for (int j = 0; j < XD; ++j) t[j] = (short)f2bf(sc * p[j]);
            // slot 5 carries the scaled bias (pairs with xs slot5 = 1.0):
            // r,z: full bias (bih+bhh); n: input-side bias only.
            float b = (g < 2) ? (sc * (bih[gcol] + bhh[gcol]))
                              : (sc * bih[gcol]);
            t[XD] = (short)f2bf(b);
        }
        fx[g] = t;
    }
    // n-gate hidden-side bias (multiplied by r at use, can't fold into MFMA)
    const float bhn = SC_T * bhh[2 * EH + colw];

    const v4f vzero = {0.f, 0.f, 0.f, 0.f};
    float hst[4] = {0.f, 0.f, 0.f, 0.f};
    __syncthreads();

    #pragma unroll 2
    for (int t = 0; t < S_SZ; ++t) {
        const int p = t & 1;
        v8s a[4];
        #pragma unroll
        for (int kt = 0; kt < 4; ++kt)
            a[kt] = *(const v8s*)&hb[p][n][kt * 32 + kg * 8];
        const unsigned short* xsrc = (kg == 0) ? &xs[t][n][0] : &zpad[0];
        v8s ax = *(const v8s*)xsrc;

        v4f accr  = __builtin_amdgcn_mfma_f32_16x16x32_bf16(a[0], fw[0][0], vzero, 0, 0, 0);
        v4f accz  = __builtin_amdgcn_mfma_f32_16x16x32_bf16(a[0], fw[1][0], vzero, 0, 0, 0);
        v4f acchn = __builtin_amdgcn_mfma_f32_16x16x32_bf16(a[0], fw[2][0], vzero, 0, 0, 0);
        #pragma unroll
        for (int kt = 1; kt < 4; ++kt) {
            accr  = __builtin_amdgcn_mfma_f32_16x16x32_bf16(a[kt], fw[0][kt], accr, 0, 0, 0);
            accz  = __builtin_amdgcn_mfma_f32_16x16x32_bf16(a[kt], fw[1][kt], accz, 0, 0, 0);
            acchn = __builtin_amdgcn_mfma_f32_16x16x32_bf16(a[kt], fw[2][kt], acchn, 0, 0, 0);
        }
        accr = __builtin_amdgcn_mfma_f32_16x16x32_bf16(ax, fx[0], accr, 0, 0, 0);
        accz = __builtin_amdgcn_mfma_f32_16x16x32_bf16(ax, fx[1], accz, 0, 0, 0);
        v4f accin = __builtin_amdgcn_mfma_f32_16x16x32_bf16(ax, fx[2], vzero, 0, 0, 0);

        float hnew[4];
        #pragma unroll
        for (int e = 0; e < 4; ++e) {
            float r  = frcp(1.f + fexp2(accr[e]));            // scales folded
            float z  = frcp(1.f + fexp2(accz[e]));
            float nn = 1.f - 2.f * frcp(fexp2(accin[e] + r * (acchn[e] + bhn)) + 1.f);
            float h  = nn + z * (hst[e] - nn);
            hst[e] = h;
            hnew[e] = h;
        }
        const unsigned int pk01 = cvt2bf(hnew[0], hnew[1]);
        const unsigned int pk23 = cvt2bf(hnew[2], hnew[3]);
        hb[1 - p][kg * 4 + 0][colw] = (unsigned short)(pk01 & 0xFFFFu);
        hb[1 - p][kg * 4 + 1][colw] = (unsigned short)(pk01 >> 16);
        hb[1 - p][kg * 4 + 2][colw] = (unsigned short)(pk23 & 0xFFFFu);
        hb[1 - p][kg * 4 + 3][colw] = (unsigned short)(pk23 >> 16);
        __syncthreads();
    }
    #pragma unroll
    for (int e = 0; e < 4; ++e)
        ctex[(size_t)(r0 + kg * 4 + e) * EH + colw] = f2bf(hst[e]);
}

// ---------------------------------------------------------------- fused decoder v3
// Same topology as v2 (256 blocks x 512 thr, 8 waves, r/z Whh resident in
// VGPRs, n-gate Whh in LDS). Deltas:
//  - wshn pad 264 -> 258: 264*16B/4 = 1056 ≡ 0 mod 32 banks, so the 4
//    kg-groups of every wave collided on the same banks each ds_read_b128.
//    258*16B/4 = 1032 ≡ 8 mod 32 -> kg phases {0,8,16,24}, all distinct.
//  - y staged to LDS once (640 B) instead of 4 scalar global loads per
//    thread per step (HBM/L2 latency inside the 2-barrier loop).
//  - activation scale constants pre-folded into dec weights (enc side-job).
__global__ __launch_bounds__(512)
__attribute__((amdgpu_waves_per_eu(2, 2)))
void dec_all_kernel(
    const unsigned short* __restrict__ dWhh_bf, // [768][256] bf16, SCALED
    const unsigned short* __restrict__ wihp,    // [768][136] bf16, SCALED
    const float* __restrict__ dbih,   // [768]
    const float* __restrict__ dbhh,   // [768]
    const float* __restrict__ y,      // [B][128] fp32
    const unsigned short* __restrict__ ctex,  // [B][128] bf16
    const float* __restrict__ linW,   // [4][256] fp32
    const float* __restrict__ linb,   // [4] fp32
    float* __restrict__ out)          // [B][S][4] fp32
{
    __shared__ unsigned short wshn[32 * 258 * 8];  // 129 KB n-gate Whh (frag, pad 258)
    __shared__ unsigned short hshf[32 * 16 * 8];   // 8 KB   h state (frag)
    __shared__ unsigned short lwf[32 * 16 * 8];    // 8 KB   linW (frag, 4->16 pad)
    __shared__ float ysh[16][DSTEPS];              // 640 B  y slab

    const int tid  = threadIdx.x;
    const int w    = tid >> 6;
    const int lane = tid & 63;
    const int n    = lane & 15;
    const int kg   = lane >> 4;
    const int rb   = blockIdx.x * 16;
    const int cbase = w * 32;

    // stage n-gate Whh (once; coalesced global reads)
    for (int i = tid; i < 256 * 32; i += 512) {
        int col = i >> 5, kgrp = i & 31;
        uint4 v = *(const uint4*)&dWhh_bf[(size_t)(512 + col) * 256 + kgrp * 8];
        *(uint4*)&wshn[(kgrp * 258 + col) * 8] = v;
    }
    // stage linW into frag layout
    {
        int col = tid >> 5, kgrp = tid & 31;
        unsigned short v8[8];
        #pragma unroll
        for (int j = 0; j < 8; ++j)
            v8[j] = (col < 4) ? f2bf(linW[col * 256 + kgrp * 8 + j]) : (unsigned short)0;
        *(uint4*)&lwf[(kgrp * 16 + col) * 8] = *(uint4*)v8;
    }
    // stage y slab: 16 rows x 10 steps
    if (tid < 16 * DSTEPS) {
        int row = tid / DSTEPS, tt = tid - row * DSTEPS;
        ysh[row][tt] = y[(size_t)(rb + row) * S_SZ + tt];
    }
    // h0 = 1
    for (int i = tid; i < 32 * 16 * 8; i += 512) hshf[i] = 0x3F80;

    // resident r/z B-frags: 2 gates x 2 colgroups x 8 K-tiles = 128 VGPRs
    v8s fB[2][2][8];
    #pragma unroll
    for (int g = 0; g < 2; ++g)
        #pragma unroll
        for (int cg = 0; cg < 2; ++cg)
            #pragma unroll
            for (int kt = 0; kt < 8; ++kt)
                fB[g][cg][kt] = *(const v8s*)
                    &dWhh_bf[(size_t)(g * DH + cbase + cg * 16 + n) * DH + kt * 32 + kg * 8];

    // gi = ctex @ dWih[:, :128]^T + biases (all pre-scaled); y weight per col
    v4f gi[3][2];
    float wy[3][2], bNh[2];
    #pragma unroll
    for (int g = 0; g < 3; ++g)
        #pragma unroll
        for (int cg = 0; cg < 2; ++cg) {
            int gcol = g * DH + cbase + cg * 16 + n;
            const float sc = (g < 2) ? SC_S : SC_T;
            float bb = sc * (dbih[gcol] + ((g < 2) ? dbhh[gcol] : 0.f));
            gi[g][cg] = (v4f){bb, bb, bb, bb};
            wy[g][cg] = bf2f(wihp[(size_t)gcol * 136 + 128]);   // already scaled
        }
    #pragma unroll
    for (int cg = 0; cg < 2; ++cg)
        bNh[cg] = SC_T * dbhh[2 * DH + cbase + cg * 16 + n];

    #pragma unroll
    for (int kt = 0; kt < 4; ++kt) {
        v8s a = *(const v8s*)&ctex[(size_t)(rb + n) * EH + kt * 32 + kg * 8];
        #pragma unroll
        for (int g = 0; g < 3; ++g)
            #pragma unroll
            for (int cg = 0; cg < 2; ++cg) {
                v8s b = *(const v8s*)
                    &wihp[(size_t)(g * DH + cbase + cg * 16 + n) * 136 + kt * 32 + kg * 8];
                gi[g][cg] = __builtin_amdgcn_mfma_f32_16x16x32_bf16(a, b, gi[g][cg], 0, 0, 0);
            }
    }

    const float lb = (n < 4) ? linb[n] : 0.f;
    float hprev[2][4];
    #pragma unroll
    for (int cg = 0; cg < 2; ++cg)
        #pragma unroll
        for (int e = 0; e < 4; ++e) hprev[cg][e] = 1.0f;

    __syncthreads();

    for (int t = 0; t < DSTEPS; ++t) {
        float yv[4];
        #pragma unroll
        for (int e = 0; e < 4; ++e)
            yv[e] = ysh[kg * 4 + e][t];

        v4f ar[2], az[2], an[2];
        #pragma unroll
        for (int cg = 0; cg < 2; ++cg) {
            ar[cg] = (v4f){0.f, 0.f, 0.f, 0.f};
            az[cg] = (v4f){0.f, 0.f, 0.f, 0.f};
            an[cg] = (v4f){bNh[cg], bNh[cg], bNh[cg], bNh[cg]};
        }
        #pragma unroll
        for (int kt = 0; kt < 8; ++kt) {
            v8s a = *(const v8s*)&hshf[((kt * 4 + kg) * 16 + n) * 8];
            #pragma unroll
            for (int cg = 0; cg < 2; ++cg) {
                v8s bn_ = *(const v8s*)&wshn[((kt * 4 + kg) * 258 + cbase + cg * 16 + n) * 8];
                ar[cg] = __builtin_amdgcn_mfma_f32_16x16x32_bf16(a, fB[0][cg][kt], ar[cg], 0, 0, 0);
                az[cg] = __builtin_amdgcn_mfma_f32_16x16x32_bf16(a, fB[1][cg][kt], az[cg], 0, 0, 0);
                an[cg] = __builtin_amdgcn_mfma_f32_16x16x32_bf16(a, bn_,           an[cg], 0, 0, 0);
            }
        }
        __syncthreads();   // all reads of h_t complete

        #pragma unroll
        for (int cg = 0; cg < 2; ++cg) {
            const int chi = 4 * w + 2 * cg + (n >> 3);   // (col>>3)
            #pragma unroll
            for (int e = 0; e < 4; ++e) {
                float r  = frcp(1.f + fexp2(gi[0][cg][e] + yv[e] * wy[0][cg] + ar[cg][e]));
                float z  = frcp(1.f + fexp2(gi[1][cg][e] + yv[e] * wy[1][cg] + az[cg][e]));
                float nn = 1.f - 2.f * frcp(
                    fexp2(gi[2][cg][e] + yv[e] * wy[2][cg] + r * an[cg][e]) + 1.f);
                float h  = nn + z * (hprev[cg][e] - nn);
                hprev[cg][e] = h;
                hshf[(chi * 16 + kg * 4 + e) * 8 + (n & 7)] = f2bf(h);
            }
        }
        __syncthreads();   // h_{t+1} visible

        if (w == 0) {      // out-proj (overlaps other waves' next MFMA phase)
            v4f o4 = {0.f, 0.f, 0.f, 0.f};
            #pragma unroll
            for (int kt = 0; kt < 8; ++kt) {
                v8s a = *(const v8s*)&hshf[((kt * 4 + kg) * 16 + n) * 8];
                v8s b = *(const v8s*)&lwf[((kt * 4 + kg) * 16 + n) * 8];
                o4 = __builtin_amdgcn_mfma_f32_16x16x32_bf16(a, b, o4, 0, 0, 0);
            }
            if (n < 4) {
                #pragma unroll
                for (int e = 0; e < 4; ++e)
                    out[(size_t)(rb + kg * 4 + e) * (S_SZ * 4) + t * 4 + n] = o4[e] + lb;
            }
        }
    }

    // tail pad: out[:, 10:, :] = 1.0
    for (int j = tid; j < 16 * 512; j += 512) {
        int row = j >> 9, c = j & 511;
        if (c >= DSTEPS * 4) out[(size_t)(rb + row) * 512 + c] = 1.0f;
    }
}

// ---------------------------------------------------------------- launch
extern "C" void kernel_launch(void* const* d_in, const int* in_sizes, int n_in,
                              void* d_out, int out_size, void* d_ws, size_t ws_size,
                              hipStream_t stream)
{
    const float* x    = (const float*)d_in[0];
    const float* y    = (const float*)d_in[1];
    const float* eWih = (const float*)d_in[2];
    const float* eWhh = (const float*)d_in[3];
    const float* ebih = (const float*)d_in[4];
    const float* ebhh = (const float*)d_in[5];
    const float* dWih = (const float*)d_in[6];
    const float* dWhh = (const float*)d_in[7];
    const float* dbih = (const float*)d_in[8];
    const float* dbhh = (const float*)d_in[9];
    const float* linW = (const float*)d_in[10];
    const float* linb = (const float*)d_in[11];
    float* out = (float*)d_out;

    char* ws = (char*)d_ws;
    // ws layout (bytes):
    //   wihp     @ 0      : 768*136*2 = 208896
    //   dWhh_bf  @ 208896 : 768*256*2 = 393216  -> 602112
    //   ctex     @ 602112 : 4096*128*2 = 1048576 -> 1650688
    unsigned short* wihp    = (unsigned short*)(ws);
    unsigned short* dWhh_bf = (unsigned short*)(ws + 208896);
    unsigned short* ctex    = (unsigned short*)(ws + 602112);

    enc_kernel<<<256, 512, 0, stream>>>(x, eWih, eWhh, ebih, ebhh,
                                        dWih, dWhh, wihp, dWhh_bf, ctex);
    dec_all_kernel<<<256, 512, 0, stream>>>(dWhh_bf, wihp, dbih, dbhh, y,
                                            ctex, linW, linb, out);
}